// Round 6
// baseline (208.316 us; speedup 1.0000x reference)
//
#include <hip/hip_runtime.h>
#include <math.h>

#define Bn 16
#define Gn 2048
#define Cn 128
#define Kn 16
#define SCAP 33    // survivor slice cap per (query,sub); mean ~8, stride 33 -> bank spread

__device__ __forceinline__ float med3f(float a, float b, float c) {
#if __has_builtin(__builtin_amdgcn_fmed3f)
    return __builtin_amdgcn_fmed3f(a, b, c);
#else
    return fmaxf(fminf(a, b), fminf(fmaxf(a, b), c));
#endif
}

// BIT-IDENTICAL everywhere (self-consistent fp ranking incl. tie detection).
__device__ __forceinline__ float dist2(const float4 me, const float4 p) {
    float dot = fmaf(me.z, p.z, fmaf(me.y, p.y, me.x * p.x));
    return fmaf(-2.0f, dot, me.w + p.w);
}

__device__ __forceinline__ void ins16(float (&d)[16], float v) {
    float prev = d[0];
    d[0] = fminf(d[0], v);
    #pragma unroll
    for (int t = 1; t < 16; ++t) { float cur = d[t]; d[t] = med3f(v, prev, cur); prev = cur; }
}

// exact bitonic min-merge of sorted d[16] across the 8 lanes of a group
__device__ __forceinline__ void merge8(float (&d)[16]) {
    #pragma unroll
    for (int m = 1; m < 8; m <<= 1) {
        float e[16];
        #pragma unroll
        for (int t = 0; t < 16; ++t) e[t] = __shfl_xor(d[t], m);
        float x[16];
        #pragma unroll
        for (int t = 0; t < 16; ++t) x[t] = fminf(d[t], e[15 - t]);
        #pragma unroll
        for (int k = 8; k; k >>= 1) {
            #pragma unroll
            for (int t = 0; t < 16; ++t)
                if (!(t & k)) {
                    float lo = fminf(x[t], x[t + k]);
                    float hi = fmaxf(x[t], x[t + k]);
                    x[t] = lo; x[t + k] = hi;
                }
        }
        #pragma unroll
        for (int t = 0; t < 16; ++t) d[t] = x[t];
    }
}

// ---------------------------------------------------------------------------
// Kernel 1: KNN top-16, sample->filter->select with private survivor slices.
// 1024 blocks: b=(x&7)|((x>>3)&1)<<3, chunk=x>>4; 32 queries/block.
// lane = qg*8+sub; slice id = w*64+lane (= q*8+sub), stride 33 ushorts.
// ---------------------------------------------------------------------------
__global__ __launch_bounds__(256) void knn_kernel(const float* __restrict__ xyz,
                                                  int* __restrict__ idx_out) {
    __shared__ float4 pts[Gn];                      // 32 KB
    __shared__ unsigned short sbuf[256 * SCAP];     // 16.9 KB private slices
    __shared__ int outb[32 * 16];                   // 2 KB
    __shared__ int tieb[32 * 16];                   // 2 KB
    // total 53,760 B -> 3 blocks/CU

    const int x     = blockIdx.x;
    const int b     = (x & 7) | (((x >> 3) & 1) << 3);
    const int chunk = x >> 4;
    const int tid   = threadIdx.x;
    const int lane  = tid & 63;
    const int w     = tid >> 6;
    const int sub   = lane & 7;
    const int q     = w * 8 + (lane >> 3);
    const int g     = chunk * 32 + q;
    const int bs    = (w * 64 + lane) * SCAP;       // my private slice base

    const float* xb = xyz + (size_t)b * Gn * 3;
    for (int i = tid; i < Gn; i += 256) {
        float px = xb[i * 3 + 0], py = xb[i * 3 + 1], pz = xb[i * 3 + 2];
        pts[i] = make_float4(px, py, pz, px * px + py * py + pz * pz);
    }
    __syncthreads();

    const float4 me = pts[g];
    const int base = sub << 8;
    const int c    = (37 * sub) & 255;              // bank stagger

    // ---- phase A: exact top16 of 512-sample (64/lane) -> conservative T0
    float d[16];
    #pragma unroll
    for (int t = 0; t < 16; ++t) d[t] = INFINITY;
    for (int j = 0; j < 64; j += 4) {
        float4 p0 = pts[base + ((j + 0 + c) & 255)];
        float4 p1 = pts[base + ((j + 1 + c) & 255)];
        float4 p2 = pts[base + ((j + 2 + c) & 255)];
        float4 p3 = pts[base + ((j + 3 + c) & 255)];
        ins16(d, dist2(me, p0)); ins16(d, dist2(me, p1));
        ins16(d, dist2(me, p2)); ins16(d, dist2(me, p3));
    }
    merge8(d);
    const float T0 = d[15];                         // >= true 16th smallest

    // ---- phase B: filter scan, private-slice append (no ballots, no atomics)
    int cnt = 0;
    for (int j = 0; j < 256; j += 4) {
        int h0 = base + ((j + 0 + c) & 255);
        int h1 = base + ((j + 1 + c) & 255);
        int h2 = base + ((j + 2 + c) & 255);
        int h3 = base + ((j + 3 + c) & 255);
        float v0 = dist2(me, pts[h0]);
        float v1 = dist2(me, pts[h1]);
        float v2 = dist2(me, pts[h2]);
        float v3 = dist2(me, pts[h3]);
        if (v0 <= T0) { if (cnt < SCAP) sbuf[bs + cnt] = (unsigned short)h0; cnt++; }
        if (v1 <= T0) { if (cnt < SCAP) sbuf[bs + cnt] = (unsigned short)h1; cnt++; }
        if (v2 <= T0) { if (cnt < SCAP) sbuf[bs + cnt] = (unsigned short)h2; cnt++; }
        if (v3 <= T0) { if (cnt < SCAP) sbuf[bs + cnt] = (unsigned short)h3; cnt++; }
    }
    const int S = (cnt > SCAP) ? SCAP : cnt;        // union over 8 subs >= 16

    // ---- phase C: exact top16 of survivors -> exact T
    #pragma unroll
    for (int t = 0; t < 16; ++t) d[t] = INFINITY;
    for (int t = 0; t < S; ++t) {
        float4 p = pts[sbuf[bs + t]];
        ins16(d, dist2(me, p));
    }
    merge8(d);
    const float T = d[15];

    // ---- phase D: emit index set; converged trip count for ballots
    int maxc = S;
    #pragma unroll
    for (int m = 1; m < 8; m <<= 1) { int o = __shfl_xor(maxc, m); maxc = (o > maxc) ? o : maxc; }

    const unsigned lowm = (1u << sub) - 1;
    const int shft = lane & 56;
    int nl = 0, nt = 0;
    for (int t = 0; t < maxc; ++t) {
        bool act = (t < S);
        int h = act ? sbuf[bs + t] : 0;
        float v = dist2(me, pts[h]);
        bool pl = act && (v < T);
        bool pt = act && (v == T);
        unsigned long long ml = __ballot(pl);
        unsigned long long mt = __ballot(pt);
        unsigned gml = (unsigned)(ml >> shft) & 0xFFu;
        unsigned gmt = (unsigned)(mt >> shft) & 0xFFu;
        if (pl) outb[q * 16 + nl + __popc(gml & lowm)] = h;            // total < 16
        if (pt) { int pp = nt + __popc(gmt & lowm); if (pp < 16) tieb[q * 16 + pp] = h; }
        nl += __popc(gml);
        nt += __popc(gmt);
    }
    if (sub == 0) {
        int mfill = nl;
        int need  = 16 - mfill;
        int tc = (nt > 16) ? 16 : nt;
        for (int s = 0; s < need; ++s) {
            int best = 0x7fffffff, bp = -1;
            for (int u = 0; u < tc; ++u) {
                int vv = tieb[q * 16 + u];
                if (vv < best) { best = vv; bp = u; }
            }
            if (bp >= 0) { tieb[q * 16 + bp] = 0x7fffffff; outb[q * 16 + mfill + s] = best; }
        }
    }
    __syncthreads();

    int* op = idx_out + ((size_t)b * Gn + (size_t)chunk * 32) * Kn;
    for (int t = tid; t < 512; t += 256) op[t] = outb[t];
}

// ---------------------------------------------------------------------------
// Kernel 2: gather + L2 pool + 2-layer MLP. 1024 blocks x 32 rows; 256 thr.
// Small LDS (19 KB) -> high occupancy hides W-stream + gather latency.
// ---------------------------------------------------------------------------
__device__ __forceinline__ float gelu_exact(float x) {
    return 0.5f * x * (1.0f + erff(x * 0.70710678118654752440f));
}

__global__ __launch_bounds__(256) void pm_kernel(const float* __restrict__ feat,
                                                 const int* __restrict__ idx,
                                                 const float* __restrict__ W1,
                                                 const float* __restrict__ b1,
                                                 const float* __restrict__ W2,
                                                 const float* __restrict__ b2,
                                                 float* __restrict__ out) {
    __shared__ float At[32 * 132];                  // 16.9 KB, padded rows
    __shared__ int   qidx[32 * 16];                 // 2 KB staged indices

    const int x     = blockIdx.x;
    const int b     = (x & 7) | (((x >> 3) & 1) << 3);   // XCD-local feat batches
    const int chunk = x >> 4;
    const int tid   = threadIdx.x;
    const int lane  = tid & 63;
    const int w     = tid >> 6;
    const size_t rowbase = (size_t)b * Gn + (size_t)chunk * 32;

    const int* ip = idx + rowbase * Kn;
    for (int t = tid; t < 512; t += 256) qidx[t] = ip[t];
    __syncthreads();

    // ---- gather + pool: half-wave per query, float4 lanes (512B coalesced)
    const float4* fb4 = (const float4*)(feat + (size_t)b * Gn * Cn);
    const int cl = lane & 31;
    #pragma unroll
    for (int pass = 0; pass < 4; ++pass) {
        int qq = w * 8 + pass * 2 + (lane >> 5);
        float4 a = make_float4(0.f, 0.f, 0.f, 0.f);
        #pragma unroll
        for (int half = 0; half < 2; ++half) {
            int hs[8]; float4 f[8];
            #pragma unroll
            for (int k = 0; k < 8; ++k) hs[k] = qidx[qq * 16 + half * 8 + k];
            #pragma unroll
            for (int k = 0; k < 8; ++k) f[k] = fb4[(size_t)hs[k] * 32 + cl];
            #pragma unroll
            for (int k = 0; k < 8; ++k) {
                a.x = fmaf(f[k].x, f[k].x, a.x);
                a.y = fmaf(f[k].y, f[k].y, a.y);
                a.z = fmaf(f[k].z, f[k].z, a.z);
                a.w = fmaf(f[k].w, f[k].w, a.w);
            }
        }
        float4 r = make_float4(sqrtf(a.x), sqrtf(a.y), sqrtf(a.z), sqrtf(a.w));
        *(float4*)&At[qq * 132 + cl * 4] = r;
    }
    __syncthreads();

    // ---- MLP: thread = 2 rows x 8 cols; register-pipelined W streams
    const int j0 = tid & 15;                        // float4-cols j0*2, j0*2+1
    const int rg = tid >> 4;                        // rows rg*2, rg*2+1
    float acc[2][8];

    // layer 1
    {
        const float4* Wv = (const float4*)W1;
        float4 ba = ((const float4*)b1)[j0 * 2];
        float4 bb = ((const float4*)b1)[j0 * 2 + 1];
        #pragma unroll
        for (int r = 0; r < 2; ++r) {
            acc[r][0] = ba.x; acc[r][1] = ba.y; acc[r][2] = ba.z; acc[r][3] = ba.w;
            acc[r][4] = bb.x; acc[r][5] = bb.y; acc[r][6] = bb.z; acc[r][7] = bb.w;
        }
        float4 cw[4][2];
        #pragma unroll
        for (int u = 0; u < 4; ++u) {
            cw[u][0] = Wv[u * 32 + j0 * 2];
            cw[u][1] = Wv[u * 32 + j0 * 2 + 1];
        }
        for (int i = 0; i < 128; i += 4) {
            float4 nw[4][2];
            int ii = (i + 4) & 127;
            #pragma unroll
            for (int u = 0; u < 4; ++u) {
                nw[u][0] = Wv[(ii + u) * 32 + j0 * 2];
                nw[u][1] = Wv[(ii + u) * 32 + j0 * 2 + 1];
            }
            #pragma unroll
            for (int r = 0; r < 2; ++r) {
                float4 a = *(const float4*)&At[(rg * 2 + r) * 132 + i];
                float av[4] = {a.x, a.y, a.z, a.w};
                #pragma unroll
                for (int u = 0; u < 4; ++u) {
                    acc[r][0] = fmaf(av[u], cw[u][0].x, acc[r][0]);
                    acc[r][1] = fmaf(av[u], cw[u][0].y, acc[r][1]);
                    acc[r][2] = fmaf(av[u], cw[u][0].z, acc[r][2]);
                    acc[r][3] = fmaf(av[u], cw[u][0].w, acc[r][3]);
                    acc[r][4] = fmaf(av[u], cw[u][1].x, acc[r][4]);
                    acc[r][5] = fmaf(av[u], cw[u][1].y, acc[r][5]);
                    acc[r][6] = fmaf(av[u], cw[u][1].z, acc[r][6]);
                    acc[r][7] = fmaf(av[u], cw[u][1].w, acc[r][7]);
                }
            }
            #pragma unroll
            for (int u = 0; u < 4; ++u) { cw[u][0] = nw[u][0]; cw[u][1] = nw[u][1]; }
        }
    }
    __syncthreads();
    #pragma unroll
    for (int r = 0; r < 2; ++r) {
        float4 g0, g1;
        g0.x = gelu_exact(acc[r][0]); g0.y = gelu_exact(acc[r][1]);
        g0.z = gelu_exact(acc[r][2]); g0.w = gelu_exact(acc[r][3]);
        g1.x = gelu_exact(acc[r][4]); g1.y = gelu_exact(acc[r][5]);
        g1.z = gelu_exact(acc[r][6]); g1.w = gelu_exact(acc[r][7]);
        *(float4*)&At[(rg * 2 + r) * 132 + j0 * 8]     = g0;
        *(float4*)&At[(rg * 2 + r) * 132 + j0 * 8 + 4] = g1;
    }
    __syncthreads();

    // layer 2
    {
        const float4* Wv = (const float4*)W2;
        float4 ba = ((const float4*)b2)[j0 * 2];
        float4 bb = ((const float4*)b2)[j0 * 2 + 1];
        #pragma unroll
        for (int r = 0; r < 2; ++r) {
            acc[r][0] = ba.x; acc[r][1] = ba.y; acc[r][2] = ba.z; acc[r][3] = ba.w;
            acc[r][4] = bb.x; acc[r][5] = bb.y; acc[r][6] = bb.z; acc[r][7] = bb.w;
        }
        float4 cw[4][2];
        #pragma unroll
        for (int u = 0; u < 4; ++u) {
            cw[u][0] = Wv[u * 32 + j0 * 2];
            cw[u][1] = Wv[u * 32 + j0 * 2 + 1];
        }
        for (int i = 0; i < 128; i += 4) {
            float4 nw[4][2];
            int ii = (i + 4) & 127;
            #pragma unroll
            for (int u = 0; u < 4; ++u) {
                nw[u][0] = Wv[(ii + u) * 32 + j0 * 2];
                nw[u][1] = Wv[(ii + u) * 32 + j0 * 2 + 1];
            }
            #pragma unroll
            for (int r = 0; r < 2; ++r) {
                float4 a = *(const float4*)&At[(rg * 2 + r) * 132 + i];
                float av[4] = {a.x, a.y, a.z, a.w};
                #pragma unroll
                for (int u = 0; u < 4; ++u) {
                    acc[r][0] = fmaf(av[u], cw[u][0].x, acc[r][0]);
                    acc[r][1] = fmaf(av[u], cw[u][0].y, acc[r][1]);
                    acc[r][2] = fmaf(av[u], cw[u][0].z, acc[r][2]);
                    acc[r][3] = fmaf(av[u], cw[u][0].w, acc[r][3]);
                    acc[r][4] = fmaf(av[u], cw[u][1].x, acc[r][4]);
                    acc[r][5] = fmaf(av[u], cw[u][1].y, acc[r][5]);
                    acc[r][6] = fmaf(av[u], cw[u][1].z, acc[r][6]);
                    acc[r][7] = fmaf(av[u], cw[u][1].w, acc[r][7]);
                }
            }
            #pragma unroll
            for (int u = 0; u < 4; ++u) { cw[u][0] = nw[u][0]; cw[u][1] = nw[u][1]; }
        }
    }
    float4* outv = (float4*)out;
    #pragma unroll
    for (int r = 0; r < 2; ++r) {
        size_t row = rowbase + rg * 2 + r;
        outv[row * 32 + j0 * 2]     = make_float4(acc[r][0], acc[r][1], acc[r][2], acc[r][3]);
        outv[row * 32 + j0 * 2 + 1] = make_float4(acc[r][4], acc[r][5], acc[r][6], acc[r][7]);
    }
}

// ---------------------------------------------------------------------------
extern "C" void kernel_launch(void* const* d_in, const int* in_sizes, int n_in,
                              void* d_out, int out_size, void* d_ws, size_t ws_size,
                              hipStream_t stream) {
    const float* xyz  = (const float*)d_in[0];
    const float* feat = (const float*)d_in[1];
    const float* W1   = (const float*)d_in[2];
    const float* b1   = (const float*)d_in[3];
    const float* W2   = (const float*)d_in[4];
    const float* b2   = (const float*)d_in[5];
    float* out = (float*)d_out;

    int* idx = (int*)d_ws;   // 2 MB

    knn_kernel<<<1024, 256, 0, stream>>>(xyz, idx);
    pm_kernel <<<1024, 256, 0, stream>>>(feat, idx, W1, b1, W2, b2, out);
}